// Round 6
// baseline (146.154 us; speedup 1.0000x reference)
//
#include <hip/hip_runtime.h>
#include <hip/hip_bf16.h>

#define BIG 3.4e38f

// ---------- top-5 helpers ----------

// Merge two ascending sorted 5-lists, keep the 5 smallest in a[].
// r[k] = min over i+j=k+1 of max(a[i-1], b[j-1]); compile-time network.
__device__ __forceinline__ void merge5(float a[5], const float* b) {
    float r[5];
#pragma unroll
    for (int k = 0; k < 5; ++k) {
        float best = BIG;
#pragma unroll
        for (int i = 0; i <= k + 1; ++i) {
            const int j = k + 1 - i;
            float va = (i == 0) ? -BIG : a[i - 1];
            float vb = (j == 0) ? -BIG : b[j - 1];
            best = fminf(best, fmaxf(va, vb));
        }
        r[k] = best;
    }
#pragma unroll
    for (int k = 0; k < 5; ++k) a[k] = r[k];
}

__device__ __forceinline__ void top5_insert(float m[5], float d) {
    if (d < m[4]) {
        m[4] = d;
#pragma unroll
        for (int k = 4; k > 0; --k) {
            float lo = fminf(m[k - 1], m[k]);
            float hi = fmaxf(m[k - 1], m[k]);
            m[k - 1] = lo;
            m[k] = hi;
        }
    }
}

__device__ __forceinline__ void wave_merge_top5(float m[5]) {
#pragma unroll
    for (int off = 1; off < 64; off <<= 1) {
        float o[5];
#pragma unroll
        for (int k = 0; k < 5; ++k) o[k] = __shfl_xor(m[k], off, 64);
        merge5(m, o);
    }
}

__device__ __forceinline__ bool block_merge_top5(float m[5], float (*s_top)[5],
                                                 float r[5]) {
    const int wid = threadIdx.x >> 6;
    if ((threadIdx.x & 63) == 0) {
#pragma unroll
        for (int k = 0; k < 5; ++k) s_top[wid][k] = m[k];
    }
    __syncthreads();
    if (threadIdx.x == 0) {
#pragma unroll
        for (int k = 0; k < 5; ++k) r[k] = s_top[0][k];
        merge5(r, s_top[1]);
        merge5(r, s_top[2]);
        merge5(r, s_top[3]);
        return true;
    }
    return false;
}

// ---------- K1 (merged, latency-optimized) ----------
// Grid (253, 9).
// y<8: scale-0 chunk y. Block = ONE h-row; 256 threads = 64 w-groups (tx,
//   4 patches each) x 4 ty (2 channels each). lane = tx*4+ty puts the 4 ty
//   partners in one wave -> cross-ty acc reduction is a 2-step shfl_xor
//   butterfly, no extra LDS/global traffic. 2024 blocks -> ~8k waves
//   (~6/SIMD after VGPR cap) vs 2/SIMD before: hides global-load latency.
// y==8 (x<64): scale-1 full distance (C=128, ps=1) + block top-5 to p2b.
__global__ __launch_bounds__(256) void dist_all_kernel(
    const float* __restrict__ src0, const float* __restrict__ tgt0,
    const int* __restrict__ pos0, const float* __restrict__ src1,
    const float* __restrict__ tgt1, const int* __restrict__ pos1,
    float* __restrict__ dist0, float* __restrict__ p2b) {
    __shared__ float tl[960];      // scale0: 10*8*3*4=960; scale1: 640
    __shared__ float s_top[4][5];

    if (blockIdx.y < 8) {
        // ---- scale 0: C=64, H=W=256, ps=3, CCH=8 (2 per ty) ----
        constexpr int H = 256, W = 256, HW = H * W, T = 10, CCH = 8;
        constexpr int PLANE = 253 * 256;
        const int c0 = blockIdx.y * CCH;

        for (int idx = threadIdx.x; idx < T * CCH * 9; idx += 256) {
            int t = idx / (CCH * 9);
            int rem = idx - t * (CCH * 9);
            int cc = rem / 9;
            int r2 = rem - cc * 9;
            int i = r2 / 3, j = r2 - i * 3;
            int th = pos0[2 * t], tw = pos0[2 * t + 1];
            tl[((t * CCH + cc) * 3 + i) * 4 + j] =
                tgt0[(size_t)(c0 + cc) * HW + (th + i) * W + (tw + j)];
        }
        __syncthreads();

        const int tx = threadIdx.x >> 2;            // 0..63 -> w-group
        const int ty = threadIdx.x & 3;             // 0..3 -> channel pair
        const int h = blockIdx.x;                   // 0..252, no clamp needed
        const int w0 = tx * 4;                      // 0..252
        const int bw = (w0 <= 248) ? w0 + 4 : 250;  // clamped 2nd col (8B ok)

        float acc[T][4];
#pragma unroll
        for (int t = 0; t < T; ++t)
#pragma unroll
            for (int n = 0; n < 4; ++n) acc[t][n] = 0.f;

        const float* sb = src0 + (size_t)(c0 + ty * 2) * HW + h * W;
#pragma unroll
        for (int ccl = 0; ccl < 2; ++ccl) {
            const float* row0 = sb + (size_t)ccl * HW;
            const int cc = ty * 2 + ccl;
#pragma unroll
            for (int i = 0; i < 3; ++i) {
                const float4 a = *(const float4*)(row0 + i * W + w0);
                const float2 b = *(const float2*)(row0 + i * W + bw);
                const float r[6] = {a.x, a.y, a.z, a.w, b.x, b.y};
#pragma unroll
                for (int t = 0; t < T; ++t) {
                    const float4 tv =
                        *(const float4*)&tl[((t * CCH + cc) * 3 + i) * 4];
#pragma unroll
                    for (int n = 0; n < 4; ++n)
                        acc[t][n] += fabsf(r[n] - tv.x) +
                                     fabsf(r[n + 1] - tv.y) +
                                     fabsf(r[n + 2] - tv.z);
                }
            }
        }

        // Cross-ty (lane&3) butterfly reduction; ty==0 lanes hold the sum.
#pragma unroll
        for (int t = 0; t < T; ++t)
#pragma unroll
            for (int n = 0; n < 4; ++n) {
                float v = acc[t][n];
                v += __shfl_xor(v, 1, 64);
                v += __shfl_xor(v, 2, 64);
                acc[t][n] = v;
            }
        if (ty == 0) {
            float* dp = dist0 + (size_t)blockIdx.y * T * PLANE + h * 256 + w0;
#pragma unroll
            for (int t = 0; t < T; ++t) {
                float4 o = {acc[t][0], acc[t][1], acc[t][2], acc[t][3]};
                *(float4*)(dp + (size_t)t * PLANE) = o;
            }
        }
    } else {
        // ---- scale 1: C=128, H=W=128, ps=1 — full dist + block top-5 ----
        if (blockIdx.x >= 64) return;
        constexpr int H = 128, W = 128, HW = H * W, T = 5, C = 128;
        for (int idx = threadIdx.x; idx < T * C; idx += 256) {
            int t = idx / C, cc = idx - t * C;
            tl[idx] =
                tgt1[(size_t)cc * HW + pos1[2 * t] * W + pos1[2 * t + 1]];
        }
        __syncthreads();

        const int w = threadIdx.x & 127;
        const int h = blockIdx.x * 2 + (threadIdx.x >> 7);  // 0..127
        float acc[T] = {0.f, 0.f, 0.f, 0.f, 0.f};
        const float* sp = src1 + h * W + w;
        for (int cc = 0; cc < C; ++cc) {
            const float v = sp[(size_t)cc * HW];
#pragma unroll
            for (int t = 0; t < T; ++t) acc[t] += fabsf(v - tl[t * C + cc]);
        }
        const bool valid = (h < 127) && (w < 127);
#pragma unroll
        for (int t = 0; t < T; ++t) {
            float m[5] = {valid ? acc[t] : BIG, BIG, BIG, BIG, BIG};
            wave_merge_top5(m);
            float r[5];
            if (block_merge_top5(m, s_top, r)) {
                float* dst = p2b + (t * 64 + blockIdx.x) * 5;
#pragma unroll
                for (int k = 0; k < 5; ++k) dst[k] = r[k];
            }
            __syncthreads();  // s_top reuse across targets
        }
    }
}

// ---------- K2: scale-0 per-target block top-5 over summed planes -------
template <int PLANE, int ROWW, int VALIDW, int NCH, int T, int NB>
__global__ __launch_bounds__(256) void top5_stage_kernel(
    const float* __restrict__ dist, float* __restrict__ part2) {
    __shared__ float s_top[4][5];
    const int t = blockIdx.y;
    constexpr int NF = PLANE / 4;
    constexpr int ITERS = (NF + NB * 256 - 1) / (NB * 256);
    float m[5] = {BIG, BIG, BIG, BIG, BIG};
#pragma unroll
    for (int k = 0; k < ITERS; ++k) {
        const int f = blockIdx.x * (ITERS * 256) + k * 256 + threadIdx.x;
        if (f < NF) {
            float4 s = *(const float4*)&dist[(size_t)t * PLANE + f * 4];
#pragma unroll
            for (int ch = 1; ch < NCH; ++ch) {
                float4 u =
                    *(const float4*)&dist[((size_t)ch * T + t) * PLANE + f * 4];
                s.x += u.x; s.y += u.y; s.z += u.z; s.w += u.w;
            }
            const int w0 = (f * 4) & (ROWW - 1);
            top5_insert(m, (w0 + 0 < VALIDW) ? s.x : BIG);
            top5_insert(m, (w0 + 1 < VALIDW) ? s.y : BIG);
            top5_insert(m, (w0 + 2 < VALIDW) ? s.z : BIG);
            top5_insert(m, (w0 + 3 < VALIDW) ? s.w : BIG);
        }
    }
    wave_merge_top5(m);
    float r[5];
    if (block_merge_top5(m, s_top, r)) {
        float* dst = part2 + (t * NB + blockIdx.x) * 5;
#pragma unroll
        for (int k = 0; k < 5; ++k) dst[k] = r[k];
    }
}

// ---------- K3: parallel-over-targets final merge + scalar write --------
// Output word: high16 = f32 bits, low16 = RNE bf16 bits (dtype-proof).
__global__ __launch_bounds__(256) void final_merge_kernel(
    const float* __restrict__ p2a, int na,
    const float* __restrict__ p2b, int nb,
    unsigned int* __restrict__ out) {
    __shared__ float s_sum[15];
    const int lane = threadIdx.x & 63;
    const int wv = threadIdx.x >> 6;
#pragma unroll
    for (int rt = 0; rt < 4; ++rt) {
        const int t = wv * 4 + rt;
        if (t < 15) {
            const float* base = (t < 10) ? p2a + t * na : p2b + (t - 10) * nb;
            const int n = (t < 10) ? na : nb;
            const float scale =
                (t < 10) ? 1.f / (576.f * 5.f) : 1.f / (128.f * 5.f);
            float m[5] = {BIG, BIG, BIG, BIG, BIG};
            for (int b0 = 0; b0 < n; b0 += 64)
                if (b0 + lane < n) top5_insert(m, base[b0 + lane]);
            wave_merge_top5(m);
            if (lane == 0)
                s_sum[t] = (m[0] + m[1] + m[2] + m[3] + m[4]) * scale;
        }
    }
    __syncthreads();
    if (threadIdx.x == 0) {
        float total = 0.f;
#pragma unroll
        for (int t = 0; t < 15; ++t) total += s_sum[t];
        union { float f; unsigned int i; } uf;
        uf.f = total * 0.1f;
        unsigned int bf = (uf.i + 0x7FFFu + ((uf.i >> 16) & 1u)) >> 16;
        out[0] = (uf.i & 0xFFFF0000u) | (bf & 0xFFFFu);
    }
}

// ---------- fallback (round-2 proven path, tiny ws) ----------
template <int C, int H, int PS, int WM>
__global__ __launch_bounds__(256) void dist_top5_kernel(
    const float* __restrict__ src, const float* __restrict__ tgt,
    const int* __restrict__ pos, float* __restrict__ part) {
    constexpr int W = H;
    constexpr int K = C * PS * PS;
    constexpr int P = WM * WM;
    __shared__ float tlv[K];
    __shared__ float s_top[4][5];
    const int t = blockIdx.y;
    const int th = pos[2 * t], tw = pos[2 * t + 1];
    for (int idx = threadIdx.x; idx < K; idx += 256) {
        int c = idx / (PS * PS);
        int rem = idx - c * PS * PS;
        int i = rem / PS, j = rem - i * PS;
        tlv[idx] = tgt[(c * H + th + i) * W + tw + j];
    }
    __syncthreads();
    const int p = blockIdx.x * 256 + threadIdx.x;
    float d = BIG;
    if (p < P) {
        const int h = p / WM, w = p - h * WM;
        float acc = 0.f;
        for (int c = 0; c < C; ++c)
#pragma unroll
            for (int i = 0; i < PS; ++i) {
                const float* r = src + (c * H + h + i) * W + w;
                const float* tr = &tlv[(c * PS + i) * PS];
#pragma unroll
                for (int j = 0; j < PS; ++j) acc += fabsf(r[j] - tr[j]);
            }
        d = acc;
    }
    float m[5] = {d, BIG, BIG, BIG, BIG};
    wave_merge_top5(m);
    float r[5];
    if (block_merge_top5(m, s_top, r)) {
        float* dst = part + (t * gridDim.x + blockIdx.x) * 5;
#pragma unroll
        for (int k = 0; k < 5; ++k) dst[k] = r[k];
    }
}

extern "C" void kernel_launch(void* const* d_in, const int* in_sizes, int n_in,
                              void* d_out, int out_size, void* d_ws, size_t ws_size,
                              hipStream_t stream) {
    const float* src0 = (const float*)d_in[0];  // [1,64,256,256] f32
    const float* tgt0 = (const float*)d_in[1];
    const float* src1 = (const float*)d_in[2];  // [1,128,128,128] f32
    const float* tgt1 = (const float*)d_in[3];
    const int* pos0 = (const int*)d_in[4];      // [10,2]
    const int* pos1 = (const int*)d_in[5];      // [5,2]
    unsigned int* out = (unsigned int*)d_out;

    constexpr size_t PLANE0 = 253 * 256;  // w-padded
    constexpr size_t NP2A = 10 * 16 * 5;
    constexpr size_t NP2B = 5 * 64 * 5;
    const size_t need = (8 * 10 * PLANE0 + NP2A + NP2B) * 4;

    if (ws_size >= need) {
        float* dist0 = (float*)d_ws;                 // 8 chunks x 10 t x PLANE0
        float* p2a = dist0 + 8 * 10 * PLANE0;        // scale-0 stage-2 partials
        float* p2b = p2a + NP2A;                     // scale-1 block top-5s

        // K1: scale-0 chunk partials (2024 blocks, 1 h-row each) + scale-1
        // direct top-5 (64 blocks) in one dispatch.
        dist_all_kernel<<<dim3(253, 9), 256, 0, stream>>>(
            src0, tgt0, pos0, src1, tgt1, pos1, dist0, p2b);
        // K2: scale-0 top-5 over summed chunk planes.
        top5_stage_kernel<253 * 256, 256, 253, 8, 10, 16>
            <<<dim3(16, 10), 256, 0, stream>>>(dist0, p2a);
        // K3: final merge (10 x 80 values + 5 x 320 values).
        final_merge_kernel<<<dim3(1), 256, 0, stream>>>(p2a, 80, p2b, 320, out);
    } else {
        // Fallback: round-2 proven path (~13K floats of ws).
        float* part0 = (float*)d_ws;
        float* part1 = part0 + 10 * 251 * 5;
        dist_top5_kernel<64, 256, 3, 253>
            <<<dim3(251, 10), 256, 0, stream>>>(src0, tgt0, pos0, part0);
        dist_top5_kernel<128, 128, 1, 127>
            <<<dim3(64, 5), 256, 0, stream>>>(src1, tgt1, pos1, part1);
        final_merge_kernel<<<dim3(1), 256, 0, stream>>>(part0, 1255, part1, 320, out);
    }
}